// Round 6
// baseline (737.923 us; speedup 1.0000x reference)
//
#include <hip/hip_runtime.h>

typedef float floatx4 __attribute__((ext_vector_type(4)));
typedef int intx8 __attribute__((ext_vector_type(8)));

#define GN 4096
#define GK 1024
#define BM 128
#define BN 128
#define BK 128          // K-elems (bytes) per LDS tile row
#define INVT (1.0f/0.03f)
#define NTILES 528      // 32*33/2 upper-tri tiles per modality
#define NCROSS 1024     // 32*32 cross tiles

// OCP e4m3 byte -> f32 (no NaN inputs possible from satfinite converts of N(0,1))
static __device__ __forceinline__ float fp8dec(unsigned b) {
    unsigned s = (b >> 7) & 1u, e = (b >> 3) & 0xFu, m = b & 7u;
    float v;
    if (e == 0) v = (float)m * 0.001953125f;                       // m * 2^-9
    else v = __builtin_bit_cast(float, ((e + 120u) << 23) | (m << 20));
    return s ? -v : v;
}

// One dispatch: blocks [0,GN) post rows (fp8 cast + inv-norm of decoded values),
// [GN,2GN) brand rows, [2GN,3GN) cross-diag dots over decoded fp8 values.
__global__ __launch_bounds__(256)
void prep_all(const float* __restrict__ brand, const float* __restrict__ post,
              unsigned char* __restrict__ brandq, unsigned char* __restrict__ postq,
              float* __restrict__ inv_brand, float* __restrict__ inv_post,
              float* __restrict__ dvec) {
    const int b = blockIdx.x, tid = threadIdx.x;
    const int wave = tid >> 6, lane = tid & 63;
    __shared__ float sw[4];
    float ss;
    if (b < 2 * GN) {
        const bool isPost = (b < GN);
        const int i = isPost ? b : b - GN;
        const float* row = (isPost ? post : brand) + (size_t)i * GK;
        unsigned char* rowq = (isPost ? postq : brandq) + (size_t)i * GK;
        float4 v = ((const float4*)row)[tid];          // 256 thr * 4 = 1024 elems
        int p = __builtin_amdgcn_cvt_pk_fp8_f32(v.x, v.y, 0, false);
        p = __builtin_amdgcn_cvt_pk_fp8_f32(v.z, v.w, p, true);
        ((int*)rowq)[tid] = p;
        float d0 = fp8dec(p & 0xFF), d1 = fp8dec((p >> 8) & 0xFF);
        float d2 = fp8dec((p >> 16) & 0xFF), d3 = fp8dec((p >> 24) & 0xFF);
        ss = d0 * d0 + d1 * d1 + d2 * d2 + d3 * d3;
        #pragma unroll
        for (int off = 32; off > 0; off >>= 1) ss += __shfl_down(ss, off);
        if (lane == 0) sw[wave] = ss;
        __syncthreads();
        if (tid == 0) {
            float s = sw[0] + sw[1] + sw[2] + sw[3];
            (isPost ? inv_post : inv_brand)[i] = 1.0f / sqrtf(s);
        }
    } else {
        const int i = b - 2 * GN;
        float4 pv = ((const float4*)(post  + (size_t)i * GK))[tid];
        float4 qv = ((const float4*)(brand + (size_t)i * GK))[tid];
        int p = __builtin_amdgcn_cvt_pk_fp8_f32(pv.x, pv.y, 0, false);
        p = __builtin_amdgcn_cvt_pk_fp8_f32(pv.z, pv.w, p, true);
        int q = __builtin_amdgcn_cvt_pk_fp8_f32(qv.x, qv.y, 0, false);
        q = __builtin_amdgcn_cvt_pk_fp8_f32(qv.z, qv.w, q, true);
        ss  = fp8dec(p & 0xFF)         * fp8dec(q & 0xFF);
        ss += fp8dec((p >> 8) & 0xFF)  * fp8dec((q >> 8) & 0xFF);
        ss += fp8dec((p >> 16) & 0xFF) * fp8dec((q >> 16) & 0xFF);
        ss += fp8dec((p >> 24) & 0xFF) * fp8dec((q >> 24) & 0xFF);
        #pragma unroll
        for (int off = 32; off > 0; off >>= 1) ss += __shfl_down(ss, off);
        if (lane == 0) sw[wave] = ss;
        __syncthreads();
        if (tid == 0) dvec[i] = sw[0] + sw[1] + sw[2] + sw[3];
    }
}

// Unified GEMM dispatch, MX-fp8 (unit scales). Blocks [0,NCROSS) cross tiles,
// then post-intra / brand-intra upper-tri tiles.
// LDS layout: row = 128 B; 16B-chunk at slot = chunk ^ (row&7)  (bank-conflict-free).
__global__ __launch_bounds__(256, 3)
void gemm_all(const unsigned char* __restrict__ postq, const unsigned char* __restrict__ brandq,
              const float* __restrict__ dvec,
              const float* __restrict__ inv_post, const float* __restrict__ inv_brand,
              float* __restrict__ sum_post, float* __restrict__ cnt_post,
              float* __restrict__ sum_brand, float* __restrict__ cnt_brand) {
    __shared__ __align__(16) unsigned char As[BM * BK];   // 16 KB
    __shared__ __align__(16) unsigned char Bs[BN * BK];   // 16 KB
    __shared__ float s_ia[128], s_ib[128], s_da[128], s_db[128];

    const int tid = threadIdx.x;
    const int wave = tid >> 6, lane = tid & 63;
    const int wm = (wave >> 1) * 64, wn = (wave & 1) * 64;

    int idx = blockIdx.x;
    const unsigned char *A, *B;
    float *srow, *scol, *crow, *ccol;
    int bm, bn;
    bool is_cross, do_cols;

    if (idx < NCROSS) {
        is_cross = true; do_cols = true;
        bm = (idx >> 5) * BM; bn = (idx & 31) * BN;
        A = postq; B = brandq;
        srow = sum_post; crow = cnt_post; scol = sum_brand; ccol = cnt_brand;
        if (tid < 128) { s_ia[tid] = inv_post[bm + tid] * INVT; s_da[tid] = dvec[bm + tid]; }
        else { int t2 = tid - 128; s_ib[t2] = inv_brand[bn + t2]; s_db[t2] = dvec[bn + t2]; }
    } else {
        is_cross = false;
        idx -= NCROSS;
        const unsigned char* X; const float* invx; float* sacc;
        if (idx >= NTILES) { idx -= NTILES; X = brandq; invx = inv_brand; sacc = sum_brand; }
        else               {               X = postq;  invx = inv_post;  sacc = sum_post;  }
        int J = (int)((sqrtf(8.f * idx + 1.f) - 1.f) * 0.5f);
        while ((J + 1) * (J + 2) / 2 <= idx) ++J;
        while (J * (J + 1) / 2 > idx) --J;
        const int I = idx - J * (J + 1) / 2;
        bm = I * BM; bn = J * BN;
        A = X; B = X;
        srow = sacc; scol = sacc; crow = nullptr; ccol = nullptr;
        do_cols = (I != J);
        if (tid < 128) s_ia[tid] = invx[bm + tid] * (0.8f * INVT);
        else           s_ib[tid - 128] = invx[bn + (tid - 128)];
    }
    // s_* writes covered by the first __syncthreads in the K-loop.

    // ---- K loop: 8 iterations of BK=128 ----
    // DMA: each instr stages 8 rows (1 KB); lane l -> row r0+(l>>3), LDS slot l&7,
    // global chunk (l&7)^((l>>3)&7). Wave w stages rows [32w,32w+32): 4 A + 4 B DMAs.
    const int lrow = lane & 15;
    const int kq = lane >> 4;
    const int dma_off = ((lane >> 3) * GK) + (((lane & 7) ^ ((lane >> 3) & 7)) * 16);
    floatx4 acc[4][4] = {};

    for (int k0 = 0; k0 < GK; k0 += BK) {
        #pragma unroll
        for (int s = 0; s < 4; ++s) {
            const int r0 = wave * 32 + s * 8;
            __builtin_amdgcn_global_load_lds(
                (const __attribute__((address_space(1))) void*)
                    (A + (size_t)(bm + r0) * GK + k0 + dma_off),
                (__attribute__((address_space(3))) void*)(As + r0 * BK), 16, 0, 0);
            __builtin_amdgcn_global_load_lds(
                (const __attribute__((address_space(1))) void*)
                    (B + (size_t)(bn + r0) * GK + k0 + dma_off),
                (__attribute__((address_space(3))) void*)(Bs + r0 * BK), 16, 0, 0);
        }
        __syncthreads();

        // B-frags first (kept live), A-frags streamed.
        intx8 bf[4];
        #pragma unroll
        for (int u = 0; u < 4; ++u) {
            const int m = wn + u * 16 + lrow;
            const unsigned char* rp = Bs + m * BK;
            const int h0 = ((2 * kq + 0) ^ (m & 7)) * 16;
            const int h1 = ((2 * kq + 1) ^ (m & 7)) * 16;
            int4 lo = *(const int4*)(rp + h0);
            int4 hi = *(const int4*)(rp + h1);
            bf[u][0] = lo.x; bf[u][1] = lo.y; bf[u][2] = lo.z; bf[u][3] = lo.w;
            bf[u][4] = hi.x; bf[u][5] = hi.y; bf[u][6] = hi.z; bf[u][7] = hi.w;
        }
        #pragma unroll
        for (int t = 0; t < 4; ++t) {
            const int m = wm + t * 16 + lrow;
            const unsigned char* rp = As + m * BK;
            const int h0 = ((2 * kq + 0) ^ (m & 7)) * 16;
            const int h1 = ((2 * kq + 1) ^ (m & 7)) * 16;
            int4 lo = *(const int4*)(rp + h0);
            int4 hi = *(const int4*)(rp + h1);
            intx8 af;
            af[0] = lo.x; af[1] = lo.y; af[2] = lo.z; af[3] = lo.w;
            af[4] = hi.x; af[5] = hi.y; af[6] = hi.z; af[7] = hi.w;
            #pragma unroll
            for (int u = 0; u < 4; ++u)
                acc[t][u] = __builtin_amdgcn_mfma_scale_f32_16x16x128_f8f6f4(
                    af, bf[u], acc[t][u],
                    0, 0,                       // cbsz=FP8, blgp=FP8
                    0, 0x7F7F7F7F,              // scale_a: E8M0 127 = 1.0
                    0, 0x7F7F7F7F);             // scale_b
        }
        __syncthreads();
    }

    // ---- register-lean epilogue (C/D: col=lane&15, row=(lane>>4)*4+reg) ----
    const int cn = lane & 15, rq = lane >> 4;
    float ib_c[4], db_c[4];
    #pragma unroll
    for (int u = 0; u < 4; ++u) {
        int cl = wn + u * 16 + cn;
        ib_c[u] = s_ib[cl];
        db_c[u] = is_cross ? s_db[cl] : 0.f;
    }

    float csum[4] = {}, ccnt[4] = {};
    float my_rs = 0.f, my_rc = 0.f;
    #pragma unroll
    for (int t = 0; t < 4; ++t) {
        #pragma unroll
        for (int r = 0; r < 4; ++r) {
            const int rl = wm + t * 16 + rq * 4 + r;
            const float ia = s_ia[rl];
            const float da = is_cross ? s_da[rl] : 0.f;
            const int grow = bm + rl;
            float v = 0.f, w = 0.f;
            #pragma unroll
            for (int u = 0; u < 4; ++u) {
                const float s = acc[t][u][r];
                const int gcol = bn + wn + u * 16 + cn;
                const bool diag = (grow == gcol);
                float e;
                if (is_cross) {
                    e = __expf(s * ia * ib_c[u]);
                    w += (!diag && s > da) ? 1.f : 0.f;
                    ccnt[u] += (!diag && s > db_c[u]) ? 1.f : 0.f;
                } else {
                    e = diag ? 1.0f : __expf(s * ia * ib_c[u]);
                }
                v += e;
                csum[u] += e;
            }
            v += __shfl_xor(v, 1); v += __shfl_xor(v, 2);
            v += __shfl_xor(v, 4); v += __shfl_xor(v, 8);
            if (cn == ((t << 2) | r)) my_rs = v;
            if (is_cross) {
                w += __shfl_xor(w, 1); w += __shfl_xor(w, 2);
                w += __shfl_xor(w, 4); w += __shfl_xor(w, 8);
                if (cn == ((t << 2) | r)) my_rc = w;
            }
        }
    }
    const int myrow = bm + wm + (cn >> 2) * 16 + rq * 4 + (cn & 3);
    atomicAdd(&srow[myrow], my_rs);
    if (is_cross) atomicAdd(&crow[myrow], my_rc);

    if (do_cols) {
        float my_cs = 0.f, my_cc = 0.f;
        #pragma unroll
        for (int u = 0; u < 4; ++u) {
            float v = csum[u];
            v += __shfl_xor(v, 16); v += __shfl_xor(v, 32);
            if (rq == u) my_cs = v;
            if (is_cross) {
                float w = ccnt[u];
                w += __shfl_xor(w, 16); w += __shfl_xor(w, 32);
                if (rq == u) my_cc = w;
            }
        }
        const int mycol = bn + wn + rq * 16 + cn;
        atomicAdd(&scol[mycol], my_cs);
        if (is_cross) atomicAdd(&ccol[mycol], my_cc);
    }
}

// Final per-row loss assembly + global sum
__global__ __launch_bounds__(256)
void final_loss(const float* __restrict__ sum_post, const float* __restrict__ cnt_post,
                const float* __restrict__ sum_brand, const float* __restrict__ cnt_brand,
                const float* __restrict__ dvec,
                const float* __restrict__ inv_post, const float* __restrict__ inv_brand,
                float* __restrict__ out) {
    const int i = blockIdx.x * 256 + threadIdx.x;
    float dl = dvec[i] * inv_post[i] * inv_brand[i] * INVT;
    float lp = logf(sum_post[i]);
    float lb = logf(sum_brand[i]);
    float rp = 1.0f / (4096.0f - cnt_post[i]) + 1.0f;
    float rb = 1.0f / (4096.0f - cnt_brand[i]) + 1.0f;
    float loss = 0.5f * (rb * (lb - dl) + rp * (lp - dl));
    #pragma unroll
    for (int off = 32; off > 0; off >>= 1) loss += __shfl_down(loss, off);
    __shared__ float sw[4];
    int wave = threadIdx.x >> 6, lane = threadIdx.x & 63;
    if (lane == 0) sw[wave] = loss;
    __syncthreads();
    if (threadIdx.x == 0) atomicAdd(out, sw[0] + sw[1] + sw[2] + sw[3]);
}

extern "C" void kernel_launch(void* const* d_in, const int* in_sizes, int n_in,
                              void* d_out, int out_size, void* d_ws, size_t ws_size,
                              hipStream_t stream) {
    const float* brand = (const float*)d_in[0];
    const float* post  = (const float*)d_in[1];
    float* out = (float*)d_out;

    char* ws = (char*)d_ws;
    unsigned char* postq  = (unsigned char*)ws;                          // 4 MB
    unsigned char* brandq = postq + (size_t)GN * GK;                     // 4 MB
    float* inv_post  = (float*)(brandq + (size_t)GN * GK);
    float* inv_brand = inv_post + GN;
    float* dvec      = inv_brand + GN;
    float* accs      = dvec + GN;        // [sum_post, sum_brand, cnt_post, cnt_brand]
    float* sum_post  = accs;
    float* sum_brand = accs + GN;
    float* cnt_post  = accs + 2 * GN;
    float* cnt_brand = accs + 3 * GN;

    hipMemsetAsync(d_out, 0, sizeof(float) * out_size, stream);
    hipMemsetAsync(accs, 0, sizeof(float) * 4 * GN, stream);

    prep_all<<<3 * GN, 256, 0, stream>>>(brand, post, brandq, postq,
                                         inv_brand, inv_post, dvec);
    gemm_all<<<NCROSS + 2 * NTILES, 256, 0, stream>>>(postq, brandq, dvec,
                                                      inv_post, inv_brand,
                                                      sum_post, cnt_post,
                                                      sum_brand, cnt_brand);
    final_loss<<<GN / 256, 256, 0, stream>>>(sum_post, cnt_post, sum_brand, cnt_brand,
                                             dvec, inv_post, inv_brand, out);
}

// Round 7
// 179.840 us; speedup vs baseline: 4.1032x; 4.1032x over previous
//
#include <hip/hip_runtime.h>

typedef float floatx4 __attribute__((ext_vector_type(4)));

#define GN 4096
#define GK 1024
#define BM 128
#define BN 128
#define BK 64           // K-bytes per LDS tile row (fp8: 1 B/elem) -> 16 K-iters
#define INVT (1.0f/0.03f)
#define NTILES 528      // 32*33/2 upper-tri tiles per modality
#define NCROSS 1024     // 32*32 cross tiles

// OCP e4m3 byte -> f32 (inputs are satfinite converts of N(0,1); no NaN)
static __device__ __forceinline__ float fp8dec(unsigned b) {
    unsigned s = (b >> 7) & 1u, e = (b >> 3) & 0xFu, m = b & 7u;
    float v;
    if (e == 0) v = (float)m * 0.001953125f;                       // m * 2^-9
    else v = __builtin_bit_cast(float, ((e + 120u) << 23) | (m << 20));
    return s ? -v : v;
}

// One dispatch: blocks [0,GN) post rows (fp8 cast + inv-norm of decoded values),
// [GN,2GN) brand rows, [2GN,3GN) cross-diag dots over decoded fp8 values.
// (Verified end-to-end in an earlier round.)
__global__ __launch_bounds__(256)
void prep_all(const float* __restrict__ brand, const float* __restrict__ post,
              unsigned char* __restrict__ brandq, unsigned char* __restrict__ postq,
              float* __restrict__ inv_brand, float* __restrict__ inv_post,
              float* __restrict__ dvec) {
    const int b = blockIdx.x, tid = threadIdx.x;
    const int wave = tid >> 6, lane = tid & 63;
    __shared__ float sw[4];
    float ss;
    if (b < 2 * GN) {
        const bool isPost = (b < GN);
        const int i = isPost ? b : b - GN;
        const float* row = (isPost ? post : brand) + (size_t)i * GK;
        unsigned char* rowq = (isPost ? postq : brandq) + (size_t)i * GK;
        float4 v = ((const float4*)row)[tid];          // 256 thr * 4 = 1024 elems
        int p = __builtin_amdgcn_cvt_pk_fp8_f32(v.x, v.y, 0, false);
        p = __builtin_amdgcn_cvt_pk_fp8_f32(v.z, v.w, p, true);
        ((int*)rowq)[tid] = p;
        float d0 = fp8dec(p & 0xFF), d1 = fp8dec((p >> 8) & 0xFF);
        float d2 = fp8dec((p >> 16) & 0xFF), d3 = fp8dec((p >> 24) & 0xFF);
        ss = d0 * d0 + d1 * d1 + d2 * d2 + d3 * d3;
        #pragma unroll
        for (int off = 32; off > 0; off >>= 1) ss += __shfl_down(ss, off);
        if (lane == 0) sw[wave] = ss;
        __syncthreads();
        if (tid == 0) {
            float s = sw[0] + sw[1] + sw[2] + sw[3];
            (isPost ? inv_post : inv_brand)[i] = 1.0f / sqrtf(s);
        }
    } else {
        const int i = b - 2 * GN;
        float4 pv = ((const float4*)(post  + (size_t)i * GK))[tid];
        float4 qv = ((const float4*)(brand + (size_t)i * GK))[tid];
        int p = __builtin_amdgcn_cvt_pk_fp8_f32(pv.x, pv.y, 0, false);
        p = __builtin_amdgcn_cvt_pk_fp8_f32(pv.z, pv.w, p, true);
        int q = __builtin_amdgcn_cvt_pk_fp8_f32(qv.x, qv.y, 0, false);
        q = __builtin_amdgcn_cvt_pk_fp8_f32(qv.z, qv.w, q, true);
        ss  = fp8dec(p & 0xFF)         * fp8dec(q & 0xFF);
        ss += fp8dec((p >> 8) & 0xFF)  * fp8dec((q >> 8) & 0xFF);
        ss += fp8dec((p >> 16) & 0xFF) * fp8dec((q >> 16) & 0xFF);
        ss += fp8dec((p >> 24) & 0xFF) * fp8dec((q >> 24) & 0xFF);
        #pragma unroll
        for (int off = 32; off > 0; off >>= 1) ss += __shfl_down(ss, off);
        if (lane == 0) sw[wave] = ss;
        __syncthreads();
        if (tid == 0) dvec[i] = sw[0] + sw[1] + sw[2] + sw[3];
    }
}

// Unified GEMM dispatch, non-scaled fp8 e4m3 (A/B operands = i64, 2 VGPRs).
// Blocks [0,NCROSS) cross tiles; then post-intra / brand-intra upper-tri tiles.
// LDS rows = 64 B = 4 chunks of 16 B; chunk c of row r lives at slot c^((r>>1)&3).
__global__ __launch_bounds__(256)
void gemm_all(const unsigned char* __restrict__ postq, const unsigned char* __restrict__ brandq,
              const float* __restrict__ dvec,
              const float* __restrict__ inv_post, const float* __restrict__ inv_brand,
              float* __restrict__ sum_post, float* __restrict__ cnt_post,
              float* __restrict__ sum_brand, float* __restrict__ cnt_brand,
              float* __restrict__ cnt_dummy) {
    __shared__ __align__(16) unsigned char As[BM * BK];   // 8 KB
    __shared__ __align__(16) unsigned char Bs[BN * BK];   // 8 KB
    __shared__ float s_ia[128], s_ib[128], s_da[128], s_db[128];
    __shared__ float redRS[128][2], redRC[128][2], redCS[128][2], redCC[128][2]; // 4 KB

    const int tid = threadIdx.x;
    const int wave = tid >> 6, lane = tid & 63;
    const int wm = (wave >> 1) * 64, wn = (wave & 1) * 64;

    int idx = blockIdx.x;
    const unsigned char *A, *B;
    float *srow, *scol, *crow, *ccol;
    int bm, bn;
    bool fix_diag, do_cols;

    if (idx < NCROSS) {
        fix_diag = false; do_cols = true;
        bm = (idx >> 5) * BM; bn = (idx & 31) * BN;
        A = postq; B = brandq;
        srow = sum_post; crow = cnt_post; scol = sum_brand; ccol = cnt_brand;
        if (tid < 128) { s_ia[tid] = inv_post[bm + tid] * INVT; s_da[tid] = dvec[bm + tid]; }
        else { int t2 = tid - 128; s_ib[t2] = inv_brand[bn + t2]; s_db[t2] = dvec[bn + t2]; }
    } else {
        fix_diag = true;
        idx -= NCROSS;
        const unsigned char* X; const float* invx; float* sacc;
        if (idx >= NTILES) { idx -= NTILES; X = brandq; invx = inv_brand; sacc = sum_brand; }
        else               {               X = postq;  invx = inv_post;  sacc = sum_post;  }
        int J = (int)((sqrtf(8.f * idx + 1.f) - 1.f) * 0.5f);
        while ((J + 1) * (J + 2) / 2 <= idx) ++J;
        while (J * (J + 1) / 2 > idx) --J;
        const int I = idx - J * (J + 1) / 2;
        bm = I * BM; bn = J * BN;
        A = X; B = X;
        srow = sacc; scol = sacc; crow = cnt_dummy; ccol = cnt_dummy;
        do_cols = (I != J);
        // sentinel diag: counts compare s > 1e30 -> always 0
        if (tid < 128) { s_ia[tid] = invx[bm + tid] * (0.8f * INVT); s_da[tid] = 1e30f; }
        else           { s_ib[tid - 128] = invx[bn + (tid - 128)];   s_db[tid - 128] = 1e30f; }
    }
    // s_* writes covered by the first __syncthreads in the K-loop.

    // ---- K loop: 16 iterations of BK=64 bytes ----
    // DMA per wave per iter: 2 strips x 16 rows for A and for B (1 KB each instr).
    // lane l: strip row l>>2, LDS slot l&3, global chunk (l&3)^((l>>3)&3).
    const int lrow = lane & 15;
    const int kq = lane >> 4;                 // 0..3
    const int swzkey = (lane >> 1) & 3;       // == ((row&15)>>1)&3 for row=base16+lrow
    const int dma_off = ((lane >> 2) * GK) + ((((lane & 3) ^ ((lane >> 3) & 3))) * 16);
    floatx4 acc[4][4] = {};

    for (int k0 = 0; k0 < GK; k0 += BK) {
        #pragma unroll
        for (int s = 0; s < 2; ++s) {
            const int r0 = wave * 32 + s * 16;
            __builtin_amdgcn_global_load_lds(
                (const __attribute__((address_space(1))) void*)
                    (A + (size_t)(bm + r0) * GK + k0 + dma_off),
                (__attribute__((address_space(3))) void*)(As + r0 * BK), 16, 0, 0);
            __builtin_amdgcn_global_load_lds(
                (const __attribute__((address_space(1))) void*)
                    (B + (size_t)(bn + r0) * GK + k0 + dma_off),
                (__attribute__((address_space(3))) void*)(Bs + r0 * BK), 16, 0, 0);
        }
        __syncthreads();

        #pragma unroll
        for (int sub = 0; sub < 2; ++sub) {
            // lane needs bytes [32*sub + 8*kq, +8) of its row
            const int chunk = 2 * sub + (kq >> 1);
            const int inner = (kq & 1) * 8;
            long bfr[4];
            #pragma unroll
            for (int u = 0; u < 4; ++u) {
                const int m = wn + u * 16 + lrow;
                bfr[u] = *(const long*)(Bs + m * BK + ((chunk ^ swzkey) * 16) + inner);
            }
            #pragma unroll
            for (int t = 0; t < 4; ++t) {
                const int m = wm + t * 16 + lrow;
                const long av = *(const long*)(As + m * BK + ((chunk ^ swzkey) * 16) + inner);
                #pragma unroll
                for (int u = 0; u < 4; ++u)
                    acc[t][u] = __builtin_amdgcn_mfma_f32_16x16x32_fp8_fp8(
                        av, bfr[u], acc[t][u], 0, 0, 0);
            }
        }
        __syncthreads();
    }

    // ---- unified epilogue (C/D: col=lane&15, row=(lane>>4)*4+reg) ----
    const int cn = lane & 15, rq = lane >> 4;
    float ib_c[4], db_c[4];
    #pragma unroll
    for (int u = 0; u < 4; ++u) {
        int cl = wn + u * 16 + cn;
        ib_c[u] = s_ib[cl];
        db_c[u] = s_db[cl];
    }

    float csum[4] = {}, ccnt[4] = {};
    float my_rs = 0.f, my_rc = 0.f;
    #pragma unroll
    for (int t = 0; t < 4; ++t) {
        #pragma unroll
        for (int r = 0; r < 4; ++r) {
            const int rl = wm + t * 16 + rq * 4 + r;
            const float ia = s_ia[rl];
            const float da = s_da[rl];
            const int grow = bm + rl;
            float v = 0.f, w = 0.f;
            #pragma unroll
            for (int u = 0; u < 4; ++u) {
                const float s = acc[t][u][r];
                const int gcol = bn + wn + u * 16 + cn;
                const bool diag = (grow == gcol);
                float e = __expf(s * ia * ib_c[u]);
                if (fix_diag && diag) e = 1.0f;      // intra: diag logit -> 0
                v += e;
                csum[u] += e;
                w += (!diag && s > da) ? 1.f : 0.f;
                ccnt[u] += (!diag && s > db_c[u]) ? 1.f : 0.f;
            }
            v += __shfl_xor(v, 1); v += __shfl_xor(v, 2);
            v += __shfl_xor(v, 4); v += __shfl_xor(v, 8);
            w += __shfl_xor(w, 1); w += __shfl_xor(w, 2);
            w += __shfl_xor(w, 4); w += __shfl_xor(w, 8);
            if (cn == ((t << 2) | r)) { my_rs = v; my_rc = w; }
        }
    }
    // each lane owns one row of its wm-strip; two waves share each wm
    const int rl_local = wm + (cn >> 2) * 16 + rq * 4 + (cn & 3);
    redRS[rl_local][wave & 1] = my_rs;
    redRC[rl_local][wave & 1] = my_rc;

    float my_cs = 0.f, my_cc = 0.f;
    #pragma unroll
    for (int u = 0; u < 4; ++u) {
        float v = csum[u];
        v += __shfl_xor(v, 16); v += __shfl_xor(v, 32);
        float w = ccnt[u];
        w += __shfl_xor(w, 16); w += __shfl_xor(w, 32);
        if (rq == u) { my_cs = v; my_cc = w; }
    }
    const int cl_local = wn + rq * 16 + cn;
    redCS[cl_local][wave >> 1] = my_cs;
    redCC[cl_local][wave >> 1] = my_cc;
    __syncthreads();

    if (tid < 128) {
        atomicAdd(&srow[bm + tid], redRS[tid][0] + redRS[tid][1]);
        atomicAdd(&crow[bm + tid], redRC[tid][0] + redRC[tid][1]);
    } else if (do_cols) {
        const int t2 = tid - 128;
        atomicAdd(&scol[bn + t2], redCS[t2][0] + redCS[t2][1]);
        atomicAdd(&ccol[bn + t2], redCC[t2][0] + redCC[t2][1]);
    }
}

// Final per-row loss assembly + global sum
__global__ __launch_bounds__(256)
void final_loss(const float* __restrict__ sum_post, const float* __restrict__ cnt_post,
                const float* __restrict__ sum_brand, const float* __restrict__ cnt_brand,
                const float* __restrict__ dvec,
                const float* __restrict__ inv_post, const float* __restrict__ inv_brand,
                float* __restrict__ out) {
    const int i = blockIdx.x * 256 + threadIdx.x;
    float dl = dvec[i] * inv_post[i] * inv_brand[i] * INVT;
    float lp = logf(sum_post[i]);
    float lb = logf(sum_brand[i]);
    float rp = 1.0f / (4096.0f - cnt_post[i]) + 1.0f;
    float rb = 1.0f / (4096.0f - cnt_brand[i]) + 1.0f;
    float loss = 0.5f * (rb * (lb - dl) + rp * (lp - dl));
    #pragma unroll
    for (int off = 32; off > 0; off >>= 1) loss += __shfl_down(loss, off);
    __shared__ float sw[4];
    int wave = threadIdx.x >> 6, lane = threadIdx.x & 63;
    if (lane == 0) sw[wave] = loss;
    __syncthreads();
    if (threadIdx.x == 0) atomicAdd(out, sw[0] + sw[1] + sw[2] + sw[3]);
}

extern "C" void kernel_launch(void* const* d_in, const int* in_sizes, int n_in,
                              void* d_out, int out_size, void* d_ws, size_t ws_size,
                              hipStream_t stream) {
    const float* brand = (const float*)d_in[0];
    const float* post  = (const float*)d_in[1];
    float* out = (float*)d_out;

    char* ws = (char*)d_ws;
    unsigned char* postq  = (unsigned char*)ws;                          // 4 MB
    unsigned char* brandq = postq + (size_t)GN * GK;                     // 4 MB
    float* inv_post  = (float*)(brandq + (size_t)GN * GK);
    float* inv_brand = inv_post + GN;
    float* dvec      = inv_brand + GN;
    float* accs      = dvec + GN;        // [sum_post, sum_brand, cnt_post, cnt_brand]
    float* sum_post  = accs;
    float* sum_brand = accs + GN;
    float* cnt_post  = accs + 2 * GN;
    float* cnt_brand = accs + 3 * GN;
    float* cnt_dummy = accs + 4 * GN;    // intra count sink (never read)

    hipMemsetAsync(d_out, 0, sizeof(float) * out_size, stream);
    hipMemsetAsync(accs, 0, sizeof(float) * 4 * GN, stream);

    prep_all<<<3 * GN, 256, 0, stream>>>(brand, post, brandq, postq,
                                         inv_brand, inv_post, dvec);
    gemm_all<<<NCROSS + 2 * NTILES, 256, 0, stream>>>(postq, brandq, dvec,
                                                      inv_post, inv_brand,
                                                      sum_post, cnt_post,
                                                      sum_brand, cnt_brand, cnt_dummy);
    final_loss<<<GN / 256, 256, 0, stream>>>(sum_post, cnt_post, sum_brand, cnt_brand,
                                             dvec, inv_post, inv_brand, out);
}